// Round 1
// baseline (367.406 us; speedup 1.0000x reference)
//
#include <hip/hip_runtime.h>
#include <hip/hip_bf16.h>

#define BDIM 2048
#define SEQT 2048
#define NB 2
#define NH 16
#define NKV 4
#define HD 128

typedef __bf16 bf16;
typedef __bf16 bf16x8 __attribute__((ext_vector_type(8)));
typedef float f32x4 __attribute__((ext_vector_type(4)));

__device__ inline void glds16(const bf16* g, bf16* l) {
  __builtin_amdgcn_global_load_lds(
      (const __attribute__((address_space(1))) unsigned int*)g,
      (__attribute__((address_space(3))) unsigned int*)l, 16, 0, 0);
}

// ---------- fp32 -> bf16 elementwise convert (8 elems/thread) ----------
__global__ __launch_bounds__(256) void k_convert(const float* __restrict__ in,
                                                 bf16* __restrict__ out, int n8) {
  int i = blockIdx.x * 256 + threadIdx.x;
  if (i >= n8) return;
  const float4* p = (const float4*)in + (size_t)i * 2;
  float4 a = p[0], b = p[1];
  bf16x8 o;
  o[0] = (bf16)a.x; o[1] = (bf16)a.y; o[2] = (bf16)a.z; o[3] = (bf16)a.w;
  o[4] = (bf16)b.x; o[5] = (bf16)b.y; o[6] = (bf16)b.z; o[7] = (bf16)b.w;
  *((bf16x8*)out + i) = o;
}

// ---------- transpose + convert: in (R x C) fp32 -> out (C x R) bf16 ----------
__global__ __launch_bounds__(256) void k_transpose(const float* __restrict__ in,
                                                   bf16* __restrict__ out, int R, int C) {
  __shared__ float tile[32][33];
  int c0 = blockIdx.x * 32, r0 = blockIdx.y * 32;
  int tx = threadIdx.x, ty = threadIdx.y;  // blockDim (32,8)
#pragma unroll
  for (int i = 0; i < 4; i++)
    tile[ty + i * 8][tx] = in[(size_t)(r0 + ty + i * 8) * C + c0 + tx];
  __syncthreads();
#pragma unroll
  for (int i = 0; i < 4; i++) {
    int r = ty + i * 8;
    out[(size_t)(c0 + r) * R + r0 + tx] = (bf16)tile[tx][r];
  }
}

// ---------- bf16 GEMM: C(MxN) = A(MxK) * Bt(NxK)^T, 128x128 tile ----------
template <typename OutT>
__global__ __launch_bounds__(256) void k_gemm(const bf16* __restrict__ A,
                                              const bf16* __restrict__ Bt,
                                              OutT* __restrict__ C,
                                              int M, int N, int K, int ldc) {
  __shared__ bf16 Al[128 * 32];
  __shared__ bf16 Bl[128 * 32];
  int tid = threadIdx.x;
  int m0 = blockIdx.y * 128, n0 = blockIdx.x * 128;
  int wid = tid >> 6, lane = tid & 63;
  int wr = (wid >> 1) * 64, wc = (wid & 1) * 64;
  int lr = lane & 15, lk = (lane >> 4) * 8;
  f32x4 acc[4][4] = {};

  for (int k0 = 0; k0 < K; k0 += 32) {
#pragma unroll
    for (int i = 0; i < 2; i++) {
      int idx = i * 256 + tid;
      int r = idx >> 2, kc = (idx & 3) * 8;
      glds16(A + (size_t)(m0 + r) * K + k0 + kc, Al + idx * 8);
      glds16(Bt + (size_t)(n0 + r) * K + k0 + kc, Bl + idx * 8);
    }
    __syncthreads();
    bf16x8 af[4], bfr[4];
#pragma unroll
    for (int mi = 0; mi < 4; mi++) af[mi] = *(const bf16x8*)&Al[(wr + mi * 16 + lr) * 32 + lk];
#pragma unroll
    for (int ni = 0; ni < 4; ni++) bfr[ni] = *(const bf16x8*)&Bl[(wc + ni * 16 + lr) * 32 + lk];
#pragma unroll
    for (int mi = 0; mi < 4; mi++)
#pragma unroll
      for (int ni = 0; ni < 4; ni++)
        acc[mi][ni] = __builtin_amdgcn_mfma_f32_16x16x32_bf16(af[mi], bfr[ni], acc[mi][ni], 0, 0, 0);
    __syncthreads();
  }

  int rbase = m0 + wr + ((lane >> 4) << 2);
#pragma unroll
  for (int mi = 0; mi < 4; mi++)
#pragma unroll
    for (int ni = 0; ni < 4; ni++)
#pragma unroll
      for (int r = 0; r < 4; r++) {
        int row = rbase + mi * 16 + r;
        int col = n0 + wc + ni * 16 + lr;
        C[(size_t)row * ldc + col] = (OutT)acc[mi][ni][r];
      }
}

// ---------- RoPE in-place on QKV buffer (q heads + k heads) ----------
__global__ __launch_bounds__(256) void k_rope(bf16* __restrict__ qkv,
                                              const float* __restrict__ fcos,
                                              const float* __restrict__ fsin) {
  int gid = blockIdx.x * 256 + threadIdx.x;  // B*T * 20 heads * 64 pairs
  int row = gid / 1280;
  int p = gid % 1280;
  int head = p >> 6;
  int dp = p & 63;
  int t = row & (SEQT - 1);
  int colbase = head < NH ? head * HD : NH * HD + (head - NH) * HD;
  bf16* ptr = qkv + (size_t)row * 3072 + colbase + dp * 2;
  float a = (float)ptr[0], b = (float)ptr[1];
  float c = fcos[t * 64 + dp], s = fsin[t * 64 + dp];
  ptr[0] = (bf16)(a * c - b * s);
  ptr[1] = (bf16)(a * s + b * c);
}

// ---------- fused causal flash attention, GQA 4:1 ----------
// qkv layout per row (b*T+t): [q 0..2047 | k 2048..2559 | v 2560..3071]
__global__ __launch_bounds__(256) void k_attn(const bf16* __restrict__ qkv,
                                              bf16* __restrict__ attout) {
  __shared__ bf16 Kl[64][136];
  __shared__ bf16 Vt[128][72];
  __shared__ bf16 Pl[4][16][72];
  int qt = blockIdx.x & 31;
  int bh = blockIdx.x >> 5;
  int b = bh >> 4, h = bh & 15, kvh = h >> 2;
  int tid = threadIdx.x, wid = tid >> 6, lane = tid & 63;
  int lr = lane & 15, lk = (lane >> 4) * 8;
  int q0 = qt * 64;
  const float scale = 0.08838834764831845f;

  bf16x8 qf[4];
  {
    const bf16* qb = qkv + (size_t)(b * SEQT + q0 + wid * 16 + lr) * 3072 + h * HD;
#pragma unroll
    for (int db = 0; db < 4; db++) qf[db] = *(const bf16x8*)(qb + db * 32 + lk);
  }
  float mrun[4] = {-INFINITY, -INFINITY, -INFINITY, -INFINITY};
  float lrun[4] = {0.f, 0.f, 0.f, 0.f};
  f32x4 o[8] = {};
  int nkt = qt + 1;
  int qg0 = q0 + wid * 16 + ((lane >> 4) << 2);

  for (int kt = 0; kt < nkt; kt++) {
    int kv0 = kt * 64;
    // stage K (row-major, padded) and V (transposed, swizzled)
#pragma unroll
    for (int i = 0; i < 4; i++) {
      int idx = i * 256 + tid;
      int row = idx >> 4, dc = (idx & 15) * 8;
      const bf16* g = qkv + (size_t)(b * SEQT + kv0 + row) * 3072 + 2048 + kvh * HD + dc;
      *(bf16x8*)&Kl[row][dc] = *(const bf16x8*)g;
      bf16x8 v = *(const bf16x8*)(g + 512);
#pragma unroll
      for (int j = 0; j < 8; j++) {
        int d = dc + j;
        Vt[d][row ^ (((d >> 3) & 3) << 3)] = v[j];
      }
    }
    __syncthreads();

    // S = Q K^T  (per wave: 16 q rows x 64 kv)
    f32x4 s[4] = {};
#pragma unroll
    for (int cb = 0; cb < 4; cb++)
#pragma unroll
      for (int db = 0; db < 4; db++) {
        bf16x8 kf = *(const bf16x8*)&Kl[cb * 16 + lr][db * 32 + lk];
        s[cb] = __builtin_amdgcn_mfma_f32_16x16x32_bf16(qf[db], kf, s[cb], 0, 0, 0);
      }

    // online softmax
    float pv[4][4];
    float rmax[4] = {-INFINITY, -INFINITY, -INFINITY, -INFINITY};
#pragma unroll
    for (int cb = 0; cb < 4; cb++) {
      int kvg = kv0 + cb * 16 + lr;
#pragma unroll
      for (int r = 0; r < 4; r++) {
        float v = s[cb][r] * scale;
        if (kvg > qg0 + r) v = -INFINITY;
        pv[cb][r] = v;
        rmax[r] = fmaxf(rmax[r], v);
      }
    }
#pragma unroll
    for (int mk = 1; mk <= 8; mk <<= 1)
#pragma unroll
      for (int r = 0; r < 4; r++) rmax[r] = fmaxf(rmax[r], __shfl_xor(rmax[r], mk));
    float alpha[4], rsum[4] = {0.f, 0.f, 0.f, 0.f};
#pragma unroll
    for (int r = 0; r < 4; r++) {
      float mnew = fmaxf(mrun[r], rmax[r]);
      alpha[r] = __expf(mrun[r] - mnew);
      mrun[r] = mnew;
    }
#pragma unroll
    for (int cb = 0; cb < 4; cb++)
#pragma unroll
      for (int r = 0; r < 4; r++) {
        float e = __expf(pv[cb][r] - mrun[r]);
        pv[cb][r] = e;
        rsum[r] += e;
      }
#pragma unroll
    for (int mk = 1; mk <= 8; mk <<= 1)
#pragma unroll
      for (int r = 0; r < 4; r++) rsum[r] += __shfl_xor(rsum[r], mk);
#pragma unroll
    for (int r = 0; r < 4; r++) lrun[r] = lrun[r] * alpha[r] + rsum[r];
#pragma unroll
    for (int df = 0; df < 8; df++)
#pragma unroll
      for (int r = 0; r < 4; r++) o[df][r] *= alpha[r];

    // P -> LDS (per-wave), re-read in A-fragment layout
#pragma unroll
    for (int cb = 0; cb < 4; cb++)
#pragma unroll
      for (int r = 0; r < 4; r++)
        Pl[wid][((lane >> 4) << 2) + r][cb * 16 + lr] = (bf16)pv[cb][r];
    __syncthreads();

    // O += P V
#pragma unroll
    for (int kb = 0; kb < 2; kb++) {
      bf16x8 pa = *(const bf16x8*)&Pl[wid][lr][kb * 32 + lk];
#pragma unroll
      for (int df = 0; df < 8; df++) {
        int d = df * 16 + lr;
        bf16x8 vb = *(const bf16x8*)&Vt[d][(kb * 32 + lk) ^ (((d >> 3) & 3) << 3)];
        o[df] = __builtin_amdgcn_mfma_f32_16x16x32_bf16(pa, vb, o[df], 0, 0, 0);
      }
    }
    __syncthreads();
  }

  // epilogue: divide by l, store bf16
#pragma unroll
  for (int r = 0; r < 4; r++) {
    float inv = 1.f / lrun[r];
    int qg = q0 + wid * 16 + ((lane >> 4) << 2) + r;
    bf16* ob = attout + (size_t)(b * SEQT + qg) * 2048 + h * HD;
#pragma unroll
    for (int df = 0; df < 8; df++)
      ob[df * 16 + lr] = (bf16)(o[df][r] * inv);
  }
}

extern "C" void kernel_launch(void* const* d_in, const int* in_sizes, int n_in,
                              void* d_out, int out_size, void* d_ws, size_t ws_size,
                              hipStream_t stream) {
  const float* x    = (const float*)d_in[0];
  const float* fcos = (const float*)d_in[1];
  const float* fsin = (const float*)d_in[2];
  const float* wq   = (const float*)d_in[3];
  const float* wk   = (const float*)d_in[4];
  const float* wv   = (const float*)d_in[5];
  const float* wo   = (const float*)d_in[6];
  float* out = (float*)d_out;

  // workspace layout (bytes): [XB/ATT 16.78M][W 12.58M][QKV 25.17M] = ~54.5MB
  char* ws = (char*)d_ws;
  bf16* XB  = (bf16*)ws;                                    // 4096x2048, later attn out
  bf16* W   = (bf16*)(ws + 16777216);                       // 3072x2048 (B^T panel)
  bf16* QKV = (bf16*)(ws + 16777216 + 12582912);            // 4096x3072

  dim3 tb(32, 8);
  k_transpose<<<dim3(64, 64), tb, 0, stream>>>(wq, W, 2048, 2048);
  k_transpose<<<dim3(16, 64), tb, 0, stream>>>(wk, W + 2048 * 2048, 2048, 512);
  k_transpose<<<dim3(16, 64), tb, 0, stream>>>(wv, W + 2560 * 2048, 2048, 512);
  k_convert<<<4096, 256, 0, stream>>>(x, XB, 1048576);
  k_gemm<bf16><<<dim3(24, 32), 256, 0, stream>>>(XB, W, QKV, 4096, 3072, 2048, 3072);
  k_rope<<<20480, 256, 0, stream>>>(QKV, fcos, fsin);
  k_attn<<<1024, 256, 0, stream>>>(QKV, XB);
  k_transpose<<<dim3(64, 64), tb, 0, stream>>>(wo, W, 2048, 2048);
  k_gemm<float><<<dim3(16, 32), 256, 0, stream>>>(XB, W, out, 4096, 2048, 2048, 2048);
}

// Round 3
// 256.342 us; speedup vs baseline: 1.4333x; 1.4333x over previous
//
#include <hip/hip_runtime.h>
#include <hip/hip_bf16.h>

#define SEQT 2048
#define NH 16
#define HD 128

typedef __bf16 bf16;
typedef __bf16 bf16x4 __attribute__((ext_vector_type(4)));
typedef __bf16 bf16x8 __attribute__((ext_vector_type(8)));
typedef float f32x4 __attribute__((ext_vector_type(4)));

__device__ inline void glds16(const bf16* g, bf16* l) {
  __builtin_amdgcn_global_load_lds(
      (const __attribute__((address_space(1))) unsigned int*)g,
      (__attribute__((address_space(3))) unsigned int*)l, 16, 0, 0);
}

// ---------- fp32 -> bf16 elementwise convert (8 elems/thread) ----------
__global__ __launch_bounds__(256) void k_convert(const float* __restrict__ in,
                                                 bf16* __restrict__ out, int n8) {
  int i = blockIdx.x * 256 + threadIdx.x;
  if (i >= n8) return;
  const float4* p = (const float4*)in + (size_t)i * 2;
  float4 a = p[0], b = p[1];
  bf16x8 o;
  o[0] = (bf16)a.x; o[1] = (bf16)a.y; o[2] = (bf16)a.z; o[3] = (bf16)a.w;
  o[4] = (bf16)b.x; o[5] = (bf16)b.y; o[6] = (bf16)b.z; o[7] = (bf16)b.w;
  *((bf16x8*)out + i) = o;
}

// ---------- transpose + convert: in (R x C) fp32 -> out (C x R) bf16 ----------
__global__ __launch_bounds__(256) void k_transpose(const float* __restrict__ in,
                                                   bf16* __restrict__ out, int R, int C) {
  __shared__ float tile[32][33];
  int c0 = blockIdx.x * 32, r0 = blockIdx.y * 32;
  int tx = threadIdx.x, ty = threadIdx.y;  // blockDim (32,8)
#pragma unroll
  for (int i = 0; i < 4; i++)
    tile[ty + i * 8][tx] = in[(size_t)(r0 + ty + i * 8) * C + c0 + tx];
  __syncthreads();
#pragma unroll
  for (int i = 0; i < 4; i++) {
    int r = ty + i * 8;
    out[(size_t)(c0 + r) * R + r0 + tx] = (bf16)tile[tx][r];
  }
}

// ---------- bf16 GEMM: C(MxN) = A(MxK) * Bt(NxK)^T, 128x128 tile ----------
template <typename OutT>
__global__ __launch_bounds__(256) void k_gemm(const bf16* __restrict__ A,
                                              const bf16* __restrict__ Bt,
                                              OutT* __restrict__ C,
                                              int M, int N, int K, int ldc) {
  __shared__ bf16 Al[128 * 32];
  __shared__ bf16 Bl[128 * 32];
  int tid = threadIdx.x;
  int m0 = blockIdx.y * 128, n0 = blockIdx.x * 128;
  int wid = tid >> 6, lane = tid & 63;
  int wr = (wid >> 1) * 64, wc = (wid & 1) * 64;
  int lr = lane & 15, lk = (lane >> 4) * 8;
  f32x4 acc[4][4] = {};

  for (int k0 = 0; k0 < K; k0 += 32) {
#pragma unroll
    for (int i = 0; i < 2; i++) {
      int idx = i * 256 + tid;
      int r = idx >> 2, kc = (idx & 3) * 8;
      glds16(A + (size_t)(m0 + r) * K + k0 + kc, Al + idx * 8);
      glds16(Bt + (size_t)(n0 + r) * K + k0 + kc, Bl + idx * 8);
    }
    __syncthreads();
    bf16x8 af[4], bfr[4];
#pragma unroll
    for (int mi = 0; mi < 4; mi++) af[mi] = *(const bf16x8*)&Al[(wr + mi * 16 + lr) * 32 + lk];
#pragma unroll
    for (int ni = 0; ni < 4; ni++) bfr[ni] = *(const bf16x8*)&Bl[(wc + ni * 16 + lr) * 32 + lk];
#pragma unroll
    for (int mi = 0; mi < 4; mi++)
#pragma unroll
      for (int ni = 0; ni < 4; ni++)
        acc[mi][ni] = __builtin_amdgcn_mfma_f32_16x16x32_bf16(af[mi], bfr[ni], acc[mi][ni], 0, 0, 0);
    __syncthreads();
  }

  int rbase = m0 + wr + ((lane >> 4) << 2);
#pragma unroll
  for (int mi = 0; mi < 4; mi++)
#pragma unroll
    for (int ni = 0; ni < 4; ni++)
#pragma unroll
      for (int r = 0; r < 4; r++) {
        int row = rbase + mi * 16 + r;
        int col = n0 + wc + ni * 16 + lr;
        C[(size_t)row * ldc + col] = (OutT)acc[mi][ni][r];
      }
}

// ---------- RoPE in-place on QKV buffer (q heads + k heads) ----------
__global__ __launch_bounds__(256) void k_rope(bf16* __restrict__ qkv,
                                              const float* __restrict__ fcos,
                                              const float* __restrict__ fsin) {
  int gid = blockIdx.x * 256 + threadIdx.x;  // B*T * 20 heads * 64 pairs
  int row = gid / 1280;
  int p = gid % 1280;
  int head = p >> 6;
  int dp = p & 63;
  int t = row & (SEQT - 1);
  int colbase = head < NH ? head * HD : NH * HD + (head - NH) * HD;
  bf16* ptr = qkv + (size_t)row * 3072 + colbase + dp * 2;
  float a = (float)ptr[0], b = (float)ptr[1];
  float c = fcos[t * 64 + dp], s = fsin[t * 64 + dp];
  ptr[0] = (bf16)(a * c - b * s);
  ptr[1] = (bf16)(a * s + b * c);
}

// ---------- fused causal flash attention, GQA 4:1 ----------
// qkv layout per row (b*T+t): [q 0..2047 | k 2048..2559 | v 2560..3071]
// K: linear [64][128] LDS via global_load_lds; row-XOR swizzle applied on the
//    global source slot and on the LDS read slot (same involution -> identity).
// V: Vt[d][kv ^ xv(d)] with xv(d)=((d>>3)&7)<<3; written as b64 along kv after
//    an in-register 4x8 transpose of b128 global loads; read as b128 along kv.
// P: per-wave [q'][kv] buffer (same-wave write->read, no barrier needed).
__global__ __launch_bounds__(256, 3) void k_attn(const bf16* __restrict__ qkv,
                                                 bf16* __restrict__ attout) {
  __shared__ bf16 Kl[64 * 128];
  __shared__ bf16 Vt[128][72];
  __shared__ bf16 Pl[4][16][72];
  int bid = blockIdx.x;
  int qt = 31 - (bid >> 5);  // heavy causal tiles dispatch first
  int bh = bid & 31;
  int b = bh >> 4, h = bh & 15, kvh = h >> 2;
  int tid = threadIdx.x, wid = tid >> 6, lane = tid & 63;
  int lr = lane & 15;
  int g = lane >> 4;
  int g4 = g * 4, g8 = g * 8, g16 = g * 16;
  int swz = (lr & 7) << 4;  // byte-level slot XOR for K reads
  int q0 = qt * 64;
  const float scale = 0.08838834764831845f;

  const bf16* kgbase = qkv + (size_t)b * SEQT * 3072 + 2048 + kvh * HD;
  const bf16* vgbase = kgbase + 512;

  bf16x8 qf[4];
  {
    const bf16* qb = qkv + (size_t)(b * SEQT + q0 + wid * 16 + lr) * 3072 + h * HD;
#pragma unroll
    for (int db = 0; db < 4; db++) qf[db] = *(const bf16x8*)(qb + db * 32 + g8);
  }
  float mrun[4] = {-INFINITY, -INFINITY, -INFINITY, -INFINITY};
  float lrun[4] = {0.f, 0.f, 0.f, 0.f};
  f32x4 o[8] = {};
  int nkt = qt + 1;
  int qg0 = q0 + wid * 16 + g4;

  // V staging geometry (per thread): 4 kv rows x 8 d columns
  int kq4 = (wid * 4 + g) * 4;      // kv base (0..60, step 4)
  int dc = lr * 8;                  // d base (0..120, step 8)
  int xr = (lr & 7) << 3;           // xv(d) for d in [dc, dc+8) — constant
  int kvw = kq4 ^ xr;

  for (int kt = 0; kt < nkt; kt++) {
    int kv0 = kt * 64;
    // ---- stage K via global_load_lds (source pre-swizzled per row) ----
#pragma unroll
    for (int r = 0; r < 4; r++) {
      int ci = r * 256 + tid;
      int row = ci >> 4;
      int sl = (ci & 15) ^ (row & 7);
      glds16(kgbase + (size_t)(kv0 + row) * 3072 + sl * 8, Kl + ci * 8);
    }
    // ---- stage V: b128 loads, in-reg 4x8 transpose, b64 swizzled writes ----
    {
      const bf16* vrow = vgbase + (size_t)(kv0 + kq4) * 3072 + dc;
      bf16x8 vv0 = *(const bf16x8*)(vrow);
      bf16x8 vv1 = *(const bf16x8*)(vrow + 3072);
      bf16x8 vv2 = *(const bf16x8*)(vrow + 6144);
      bf16x8 vv3 = *(const bf16x8*)(vrow + 9216);
#pragma unroll
      for (int j = 0; j < 8; j++) {
        bf16x4 w;
        w[0] = vv0[j]; w[1] = vv1[j]; w[2] = vv2[j]; w[3] = vv3[j];
        *(bf16x4*)&Vt[dc + j][kvw] = w;
      }
    }
    __syncthreads();

    // ---- S = Q K^T (swizzled conflict-free b128 reads) ----
    f32x4 s[4] = {};
    __builtin_amdgcn_s_setprio(1);
#pragma unroll
    for (int cb = 0; cb < 4; cb++) {
      const char* krow = (const char*)(Kl + (cb * 16 + lr) * 128);
#pragma unroll
      for (int db = 0; db < 4; db++) {
        bf16x8 kf = *(const bf16x8*)(krow + ((db * 64 + g16) ^ swz));
        s[cb] = __builtin_amdgcn_mfma_f32_16x16x32_bf16(qf[db], kf, s[cb], 0, 0, 0);
      }
    }
    __builtin_amdgcn_s_setprio(0);

    // ---- online softmax ----
    float pv[4][4];
    float rmax[4] = {-INFINITY, -INFINITY, -INFINITY, -INFINITY};
#pragma unroll
    for (int cb = 0; cb < 4; cb++) {
      int kvg = kv0 + cb * 16 + lr;
#pragma unroll
      for (int r = 0; r < 4; r++) {
        float v = s[cb][r] * scale;
        if (kvg > qg0 + r) v = -INFINITY;
        pv[cb][r] = v;
        rmax[r] = fmaxf(rmax[r], v);
      }
    }
#pragma unroll
    for (int mk = 1; mk <= 8; mk <<= 1)
#pragma unroll
      for (int r = 0; r < 4; r++) rmax[r] = fmaxf(rmax[r], __shfl_xor(rmax[r], mk));
    float alpha[4], rsum[4] = {0.f, 0.f, 0.f, 0.f};
#pragma unroll
    for (int r = 0; r < 4; r++) {
      float mnew = fmaxf(mrun[r], rmax[r]);
      alpha[r] = __expf(mrun[r] - mnew);
      mrun[r] = mnew;
    }
#pragma unroll
    for (int cb = 0; cb < 4; cb++)
#pragma unroll
      for (int r = 0; r < 4; r++) {
        float e = __expf(pv[cb][r] - mrun[r]);
        pv[cb][r] = e;
        rsum[r] += e;
      }
#pragma unroll
    for (int mk = 1; mk <= 8; mk <<= 1)
#pragma unroll
      for (int r = 0; r < 4; r++) rsum[r] += __shfl_xor(rsum[r], mk);
#pragma unroll
    for (int r = 0; r < 4; r++) lrun[r] = lrun[r] * alpha[r] + rsum[r];
#pragma unroll
    for (int df = 0; df < 8; df++)
#pragma unroll
      for (int r = 0; r < 4; r++) o[df][r] *= alpha[r];

    // ---- P -> per-wave LDS [q'][kv] ----
#pragma unroll
    for (int cb = 0; cb < 4; cb++)
#pragma unroll
      for (int r = 0; r < 4; r++)
        Pl[wid][g4 + r][cb * 16 + lr] = (bf16)pv[cb][r];

    // ---- O += P V ----
    __builtin_amdgcn_s_setprio(1);
#pragma unroll
    for (int kb = 0; kb < 2; kb++) {
      bf16x8 pa = *(const bf16x8*)&Pl[wid][lr][kb * 32 + g8];
#pragma unroll
      for (int df = 0; df < 8; df++) {
        int d = df * 16 + lr;
        int xv = ((d >> 3) & 7) << 3;
        bf16x8 vb = *(const bf16x8*)&Vt[d][(kb * 32 + g8) ^ xv];
        o[df] = __builtin_amdgcn_mfma_f32_16x16x32_bf16(pa, vb, o[df], 0, 0, 0);
      }
    }
    __builtin_amdgcn_s_setprio(0);
    __syncthreads();
  }

  // ---- epilogue: divide by l, store bf16 ----
#pragma unroll
  for (int r = 0; r < 4; r++) {
    float inv = 1.f / lrun[r];
    int qg = q0 + wid * 16 + g4 + r;
    bf16* ob = attout + (size_t)(b * SEQT + qg) * 2048 + h * HD;
#pragma unroll
    for (int df = 0; df < 8; df++)
      ob[df * 16 + lr] = (bf16)(o[df][r] * inv);
  }
}

extern "C" void kernel_launch(void* const* d_in, const int* in_sizes, int n_in,
                              void* d_out, int out_size, void* d_ws, size_t ws_size,
                              hipStream_t stream) {
  const float* x    = (const float*)d_in[0];
  const float* fcos = (const float*)d_in[1];
  const float* fsin = (const float*)d_in[2];
  const float* wq   = (const float*)d_in[3];
  const float* wk   = (const float*)d_in[4];
  const float* wv   = (const float*)d_in[5];
  const float* wo   = (const float*)d_in[6];
  float* out = (float*)d_out;

  // workspace layout (bytes): [XB/ATT 16.78M][W 12.58M][QKV 25.17M] = ~54.5MB
  char* ws = (char*)d_ws;
  bf16* XB  = (bf16*)ws;                                    // 4096x2048, later attn out
  bf16* W   = (bf16*)(ws + 16777216);                       // 3072x2048 (B^T panel)
  bf16* QKV = (bf16*)(ws + 16777216 + 12582912);            // 4096x3072

  dim3 tb(32, 8);
  k_transpose<<<dim3(64, 64), tb, 0, stream>>>(wq, W, 2048, 2048);
  k_transpose<<<dim3(16, 64), tb, 0, stream>>>(wk, W + 2048 * 2048, 2048, 512);
  k_transpose<<<dim3(16, 64), tb, 0, stream>>>(wv, W + 2560 * 2048, 2048, 512);
  k_convert<<<4096, 256, 0, stream>>>(x, XB, 1048576);
  k_gemm<bf16><<<dim3(24, 32), 256, 0, stream>>>(XB, W, QKV, 4096, 3072, 2048, 3072);
  k_rope<<<20480, 256, 0, stream>>>(QKV, fcos, fsin);
  k_attn<<<1024, 256, 0, stream>>>(QKV, XB);
  k_transpose<<<dim3(64, 64), tb, 0, stream>>>(wo, W, 2048, 2048);
  k_gemm<float><<<dim3(16, 32), 256, 0, stream>>>(XB, W, out, 4096, 2048, 2048, 2048);
}

// Round 4
// 242.247 us; speedup vs baseline: 1.5167x; 1.0582x over previous
//
#include <hip/hip_runtime.h>
#include <hip/hip_bf16.h>

#define SEQT 2048
#define NH 16
#define HD 128

typedef __bf16 bf16;
typedef __bf16 bf16x4 __attribute__((ext_vector_type(4)));
typedef __bf16 bf16x8 __attribute__((ext_vector_type(8)));
typedef float f32x4 __attribute__((ext_vector_type(4)));

__device__ inline void glds16(const bf16* g, bf16* l) {
  __builtin_amdgcn_global_load_lds(
      (const __attribute__((address_space(1))) unsigned int*)g,
      (__attribute__((address_space(3))) unsigned int*)l, 16, 0, 0);
}

// ---------- fp32 -> bf16 elementwise convert (8 elems/thread) ----------
__global__ __launch_bounds__(256) void k_convert(const float* __restrict__ in,
                                                 bf16* __restrict__ out, int n8) {
  int i = blockIdx.x * 256 + threadIdx.x;
  if (i >= n8) return;
  const float4* p = (const float4*)in + (size_t)i * 2;
  float4 a = p[0], b = p[1];
  bf16x8 o;
  o[0] = (bf16)a.x; o[1] = (bf16)a.y; o[2] = (bf16)a.z; o[3] = (bf16)a.w;
  o[4] = (bf16)b.x; o[5] = (bf16)b.y; o[6] = (bf16)b.z; o[7] = (bf16)b.w;
  *((bf16x8*)out + i) = o;
}

// ---------- transpose + convert: in (R x C) fp32 -> out (C x R) bf16 ----------
__global__ __launch_bounds__(256) void k_transpose(const float* __restrict__ in,
                                                   bf16* __restrict__ out, int R, int C) {
  __shared__ float tile[32][33];
  int c0 = blockIdx.x * 32, r0 = blockIdx.y * 32;
  int tx = threadIdx.x, ty = threadIdx.y;  // blockDim (32,8)
#pragma unroll
  for (int i = 0; i < 4; i++)
    tile[ty + i * 8][tx] = in[(size_t)(r0 + ty + i * 8) * C + c0 + tx];
  __syncthreads();
#pragma unroll
  for (int i = 0; i < 4; i++) {
    int r = ty + i * 8;
    out[(size_t)(c0 + r) * R + r0 + tx] = (bf16)tile[tx][r];
  }
}

// ---------- bf16 GEMM: C(MxN) = A(MxK) * Bt(NxK)^T, 128x128 tile ----------
template <typename OutT>
__global__ __launch_bounds__(256) void k_gemm(const bf16* __restrict__ A,
                                              const bf16* __restrict__ Bt,
                                              OutT* __restrict__ C,
                                              int M, int N, int K, int ldc) {
  __shared__ bf16 Al[128 * 32];
  __shared__ bf16 Bl[128 * 32];
  int tid = threadIdx.x;
  int m0 = blockIdx.y * 128, n0 = blockIdx.x * 128;
  int wid = tid >> 6, lane = tid & 63;
  int wr = (wid >> 1) * 64, wc = (wid & 1) * 64;
  int lr = lane & 15, lk = (lane >> 4) * 8;
  f32x4 acc[4][4] = {};

  for (int k0 = 0; k0 < K; k0 += 32) {
#pragma unroll
    for (int i = 0; i < 2; i++) {
      int idx = i * 256 + tid;
      int r = idx >> 2, kc = (idx & 3) * 8;
      glds16(A + (size_t)(m0 + r) * K + k0 + kc, Al + idx * 8);
      glds16(Bt + (size_t)(n0 + r) * K + k0 + kc, Bl + idx * 8);
    }
    __syncthreads();
    bf16x8 af[4], bfr[4];
#pragma unroll
    for (int mi = 0; mi < 4; mi++) af[mi] = *(const bf16x8*)&Al[(wr + mi * 16 + lr) * 32 + lk];
#pragma unroll
    for (int ni = 0; ni < 4; ni++) bfr[ni] = *(const bf16x8*)&Bl[(wc + ni * 16 + lr) * 32 + lk];
#pragma unroll
    for (int mi = 0; mi < 4; mi++)
#pragma unroll
      for (int ni = 0; ni < 4; ni++)
        acc[mi][ni] = __builtin_amdgcn_mfma_f32_16x16x32_bf16(af[mi], bfr[ni], acc[mi][ni], 0, 0, 0);
    __syncthreads();
  }

  int rbase = m0 + wr + ((lane >> 4) << 2);
#pragma unroll
  for (int mi = 0; mi < 4; mi++)
#pragma unroll
    for (int ni = 0; ni < 4; ni++)
#pragma unroll
      for (int r = 0; r < 4; r++) {
        int row = rbase + mi * 16 + r;
        int col = n0 + wc + ni * 16 + lr;
        C[(size_t)row * ldc + col] = (OutT)acc[mi][ni][r];
      }
}

// ---------- RoPE in-place on QKV buffer (q heads + k heads) ----------
__global__ __launch_bounds__(256) void k_rope(bf16* __restrict__ qkv,
                                              const float* __restrict__ fcos,
                                              const float* __restrict__ fsin) {
  int gid = blockIdx.x * 256 + threadIdx.x;  // B*T * 20 heads * 64 pairs
  int row = gid / 1280;
  int p = gid % 1280;
  int head = p >> 6;
  int dp = p & 63;
  int t = row & (SEQT - 1);
  int colbase = head < NH ? head * HD : NH * HD + (head - NH) * HD;
  bf16* ptr = qkv + (size_t)row * 3072 + colbase + dp * 2;
  float a = (float)ptr[0], b = (float)ptr[1];
  float c = fcos[t * 64 + dp], s = fsin[t * 64 + dp];
  ptr[0] = (bf16)(a * c - b * s);
  ptr[1] = (bf16)(a * s + b * c);
}

// ---------- fused causal flash attention, GQA 4:1 ----------
// Pipelined: K double-buffered in LDS via global_load_lds, V double-buffered in
// registers; prefetch for tile kt+1 issued before the compute barrier; raw
// s_barrier (no vmcnt drain) so loads stay in flight across compute (T14/T3).
// Defer-max (T13, THR=8): skip O/l rescale when the tile max doesn't grow.
// Row-sum kept as per-lane partials, reduced once at the epilogue.
__global__ __launch_bounds__(256, 2) void k_attn(const bf16* __restrict__ qkv,
                                                 bf16* __restrict__ attout) {
  __shared__ bf16 Kl[2][64 * 128];
  __shared__ bf16 Vt[128][72];
  __shared__ bf16 Pl[4][16][72];
  int bid = blockIdx.x;
  int qt = 31 - (bid >> 5);  // heavy causal tiles dispatch first
  int bh = bid & 31;
  int b = bh >> 4, h = bh & 15, kvh = h >> 2;
  int tid = threadIdx.x, wid = tid >> 6, lane = tid & 63;
  int lr = lane & 15;
  int g = lane >> 4;
  int g4 = g * 4, g8 = g * 8, g16 = g * 16;
  int swz = (lr & 7) << 4;  // byte-level slot XOR for K reads
  int q0 = qt * 64;
  const float scale = 0.08838834764831845f;

  const bf16* kgbase = qkv + (size_t)b * SEQT * 3072 + 2048 + kvh * HD;
  const bf16* vgbase = kgbase + 512;

  bf16x8 qf[4];
  {
    const bf16* qb = qkv + (size_t)(b * SEQT + q0 + wid * 16 + lr) * 3072 + h * HD;
#pragma unroll
    for (int db = 0; db < 4; db++) qf[db] = *(const bf16x8*)(qb + db * 32 + g8);
  }
  float mrun[4] = {-INFINITY, -INFINITY, -INFINITY, -INFINITY};
  float lpart[4] = {0.f, 0.f, 0.f, 0.f};  // per-lane partial row sums
  f32x4 o[8] = {};
  int nkt = qt + 1;
  int qg0 = q0 + wid * 16 + g4;

  // V staging geometry (per thread): 4 kv rows x 8 d columns
  int kq4 = (wid * 4 + g) * 4;      // kv base (0..60, step 4)
  int dc = lr * 8;                  // d base (0..120, step 8)
  int xr = (lr & 7) << 3;           // xv(d) for d in [dc, dc+8) — constant
  int kvw = kq4 ^ xr;

  // K staging geometry (per thread): 4 chunks
  // ci = r*256+tid; row = ci>>4; source slot = (ci&15) ^ (row&7)
  bf16x8 vr0, vr1, vr2, vr3;

  // ---- prologue: issue K(0) glds + V(0) reg loads ----
#pragma unroll
  for (int r = 0; r < 4; r++) {
    int ci = r * 256 + tid;
    int row = ci >> 4;
    int sl = (ci & 15) ^ (row & 7);
    glds16(kgbase + (size_t)row * 3072 + sl * 8, &Kl[0][ci * 8]);
  }
  {
    const bf16* vrow = vgbase + (size_t)kq4 * 3072 + dc;
    vr0 = *(const bf16x8*)(vrow);
    vr1 = *(const bf16x8*)(vrow + 3072);
    vr2 = *(const bf16x8*)(vrow + 6144);
    vr3 = *(const bf16x8*)(vrow + 9216);
  }

  for (int kt = 0; kt < nkt; kt++) {
    int cur = kt & 1;
    // ---- drain prefetch: K(kt) now in Kl[cur], V(kt) in vr ----
    asm volatile("s_waitcnt vmcnt(0)" ::: "memory");

    // ---- V regs -> Vt (swizzled b64 writes) ----
#pragma unroll
    for (int j = 0; j < 8; j++) {
      bf16x4 w;
      w[0] = vr0[j]; w[1] = vr1[j]; w[2] = vr2[j]; w[3] = vr3[j];
      *(bf16x4*)&Vt[dc + j][kvw] = w;
    }

    // ---- prefetch tile kt+1 (stays in flight across compute) ----
    if (kt + 1 < nkt) {
      int kv1 = (kt + 1) * 64;
      bf16* kdst = &Kl[(kt + 1) & 1][0];
#pragma unroll
      for (int r = 0; r < 4; r++) {
        int ci = r * 256 + tid;
        int row = ci >> 4;
        int sl = (ci & 15) ^ (row & 7);
        glds16(kgbase + (size_t)(kv1 + row) * 3072 + sl * 8, kdst + ci * 8);
      }
      const bf16* vrow = vgbase + (size_t)(kv1 + kq4) * 3072 + dc;
      vr0 = *(const bf16x8*)(vrow);
      vr1 = *(const bf16x8*)(vrow + 3072);
      vr2 = *(const bf16x8*)(vrow + 6144);
      vr3 = *(const bf16x8*)(vrow + 9216);
    }

    // ---- barrier (raw: do NOT drain the prefetch vmcnt) ----
    asm volatile("s_waitcnt lgkmcnt(0)" ::: "memory");
    __builtin_amdgcn_sched_barrier(0);
    __builtin_amdgcn_s_barrier();
    __builtin_amdgcn_sched_barrier(0);

    int kv0 = kt * 64;
    // ---- S = Q K^T (swizzled conflict-free b128 reads) ----
    f32x4 s[4] = {};
    __builtin_amdgcn_s_setprio(1);
#pragma unroll
    for (int cb = 0; cb < 4; cb++) {
      const char* krow = (const char*)(&Kl[cur][0] + (cb * 16 + lr) * 128);
#pragma unroll
      for (int db = 0; db < 4; db++) {
        bf16x8 kf = *(const bf16x8*)(krow + ((db * 64 + g16) ^ swz));
        s[cb] = __builtin_amdgcn_mfma_f32_16x16x32_bf16(qf[db], kf, s[cb], 0, 0, 0);
      }
    }
    __builtin_amdgcn_s_setprio(0);

    // ---- online softmax with defer-max ----
    float pv[4][4];
    float pmax[4] = {-INFINITY, -INFINITY, -INFINITY, -INFINITY};
#pragma unroll
    for (int cb = 0; cb < 4; cb++) {
      int kvg = kv0 + cb * 16 + lr;
#pragma unroll
      for (int r = 0; r < 4; r++) {
        float v = s[cb][r] * scale;
        if (kvg > qg0 + r) v = -INFINITY;
        pv[cb][r] = v;
        pmax[r] = fmaxf(pmax[r], v);
      }
    }
#pragma unroll
    for (int mk = 1; mk <= 8; mk <<= 1)
#pragma unroll
      for (int r = 0; r < 4; r++) pmax[r] = fmaxf(pmax[r], __shfl_xor(pmax[r], mk));
    float grow = fmaxf(fmaxf(pmax[0] - mrun[0], pmax[1] - mrun[1]),
                       fmaxf(pmax[2] - mrun[2], pmax[3] - mrun[3]));
    if (!__all(grow <= 8.0f)) {
#pragma unroll
      for (int r = 0; r < 4; r++) {
        float mnew = fmaxf(mrun[r], pmax[r]);
        float alpha = __expf(mrun[r] - mnew);
        mrun[r] = mnew;
        lpart[r] *= alpha;
#pragma unroll
        for (int df = 0; df < 8; df++) o[df][r] *= alpha;
      }
    }
#pragma unroll
    for (int r = 0; r < 4; r++) {
      float rs = 0.f;
#pragma unroll
      for (int cb = 0; cb < 4; cb++) {
        float e = __expf(pv[cb][r] - mrun[r]);
        pv[cb][r] = e;
        rs += e;
      }
      lpart[r] += rs;
    }

    // ---- P -> per-wave LDS [q'][kv] ----
#pragma unroll
    for (int cb = 0; cb < 4; cb++)
#pragma unroll
      for (int r = 0; r < 4; r++)
        Pl[wid][g4 + r][cb * 16 + lr] = (bf16)pv[cb][r];

    // ---- O += P V ----
    __builtin_amdgcn_s_setprio(1);
#pragma unroll
    for (int kb = 0; kb < 2; kb++) {
      bf16x8 pa = *(const bf16x8*)&Pl[wid][lr][kb * 32 + g8];
#pragma unroll
      for (int df = 0; df < 8; df++) {
        int d = df * 16 + lr;
        int xv = ((d >> 3) & 7) << 3;
        bf16x8 vb = *(const bf16x8*)&Vt[d][(kb * 32 + g8) ^ xv];
        o[df] = __builtin_amdgcn_mfma_f32_16x16x32_bf16(pa, vb, o[df], 0, 0, 0);
      }
    }
    __builtin_amdgcn_s_setprio(0);
    __builtin_amdgcn_sched_barrier(0);
    __builtin_amdgcn_s_barrier();
    __builtin_amdgcn_sched_barrier(0);
  }

  // ---- epilogue: reduce partial row sums, divide, store bf16 ----
#pragma unroll
  for (int mk = 1; mk <= 8; mk <<= 1)
#pragma unroll
    for (int r = 0; r < 4; r++) lpart[r] += __shfl_xor(lpart[r], mk);
#pragma unroll
  for (int r = 0; r < 4; r++) {
    float inv = 1.f / lpart[r];
    int qg = q0 + wid * 16 + g4 + r;
    bf16* ob = attout + (size_t)(b * SEQT + qg) * 2048 + h * HD;
#pragma unroll
    for (int df = 0; df < 8; df++)
      ob[df * 16 + lr] = (bf16)(o[df][r] * inv);
  }
}

extern "C" void kernel_launch(void* const* d_in, const int* in_sizes, int n_in,
                              void* d_out, int out_size, void* d_ws, size_t ws_size,
                              hipStream_t stream) {
  const float* x    = (const float*)d_in[0];
  const float* fcos = (const float*)d_in[1];
  const float* fsin = (const float*)d_in[2];
  const float* wq   = (const float*)d_in[3];
  const float* wk   = (const float*)d_in[4];
  const float* wv   = (const float*)d_in[5];
  const float* wo   = (const float*)d_in[6];
  float* out = (float*)d_out;

  // workspace layout (bytes): [XB/ATT 16.78M][W 12.58M][QKV 25.17M] = ~54.5MB
  char* ws = (char*)d_ws;
  bf16* XB  = (bf16*)ws;                                    // 4096x2048, later attn out
  bf16* W   = (bf16*)(ws + 16777216);                       // 3072x2048 (B^T panel)
  bf16* QKV = (bf16*)(ws + 16777216 + 12582912);            // 4096x3072

  dim3 tb(32, 8);
  k_transpose<<<dim3(64, 64), tb, 0, stream>>>(wq, W, 2048, 2048);
  k_transpose<<<dim3(16, 64), tb, 0, stream>>>(wk, W + 2048 * 2048, 2048, 512);
  k_transpose<<<dim3(16, 64), tb, 0, stream>>>(wv, W + 2560 * 2048, 2048, 512);
  k_convert<<<4096, 256, 0, stream>>>(x, XB, 1048576);
  k_gemm<bf16><<<dim3(24, 32), 256, 0, stream>>>(XB, W, QKV, 4096, 3072, 2048, 3072);
  k_rope<<<20480, 256, 0, stream>>>(QKV, fcos, fsin);
  k_attn<<<1024, 256, 0, stream>>>(QKV, XB);
  k_transpose<<<dim3(64, 64), tb, 0, stream>>>(wo, W, 2048, 2048);
  k_gemm<float><<<dim3(16, 32), 256, 0, stream>>>(XB, W, out, 4096, 2048, 2048, 2048);
}

// Round 6
// 241.560 us; speedup vs baseline: 1.5210x; 1.0028x over previous
//
#include <hip/hip_runtime.h>
#include <hip/hip_bf16.h>

#define SEQT 2048
#define NH 16
#define HD 128

typedef __bf16 bf16;
typedef __bf16 bf16x4 __attribute__((ext_vector_type(4)));
typedef __bf16 bf16x8 __attribute__((ext_vector_type(8)));
typedef float f32x4 __attribute__((ext_vector_type(4)));
typedef float f32x16 __attribute__((ext_vector_type(16)));

__device__ inline void glds16(const bf16* g, bf16* l) {
  __builtin_amdgcn_global_load_lds(
      (const __attribute__((address_space(1))) unsigned int*)g,
      (__attribute__((address_space(3))) unsigned int*)l, 16, 0, 0);
}

__device__ inline unsigned int cvtpk(float a, float b) {
  unsigned int d;
  asm("v_cvt_pk_bf16_f32 %0, %1, %2" : "=v"(d) : "v"(a), "v"(b));
  return d;
}

// ---------- fp32 -> bf16 elementwise convert (8 elems/thread) ----------
__global__ __launch_bounds__(256) void k_convert(const float* __restrict__ in,
                                                 bf16* __restrict__ out, int n8) {
  int i = blockIdx.x * 256 + threadIdx.x;
  if (i >= n8) return;
  const float4* p = (const float4*)in + (size_t)i * 2;
  float4 a = p[0], b = p[1];
  bf16x8 o;
  o[0] = (bf16)a.x; o[1] = (bf16)a.y; o[2] = (bf16)a.z; o[3] = (bf16)a.w;
  o[4] = (bf16)b.x; o[5] = (bf16)b.y; o[6] = (bf16)b.z; o[7] = (bf16)b.w;
  *((bf16x8*)out + i) = o;
}

// ---------- transpose + convert: in (R x C) fp32 -> out (C x R) bf16 ----------
__global__ __launch_bounds__(256) void k_transpose(const float* __restrict__ in,
                                                   bf16* __restrict__ out, int R, int C) {
  __shared__ float tile[32][33];
  int c0 = blockIdx.x * 32, r0 = blockIdx.y * 32;
  int tx = threadIdx.x, ty = threadIdx.y;  // blockDim (32,8)
#pragma unroll
  for (int i = 0; i < 4; i++)
    tile[ty + i * 8][tx] = in[(size_t)(r0 + ty + i * 8) * C + c0 + tx];
  __syncthreads();
#pragma unroll
  for (int i = 0; i < 4; i++) {
    int r = ty + i * 8;
    out[(size_t)(c0 + r) * R + r0 + tx] = (bf16)tile[tx][r];
  }
}

// ---------- bf16 GEMM: C(MxN) = A(MxK) * Bt(NxK)^T, 128x128 tile ----------
template <typename OutT>
__global__ __launch_bounds__(256) void k_gemm(const bf16* __restrict__ A,
                                              const bf16* __restrict__ Bt,
                                              OutT* __restrict__ C,
                                              int M, int N, int K, int ldc) {
  __shared__ bf16 Al[128 * 32];
  __shared__ bf16 Bl[128 * 32];
  int tid = threadIdx.x;
  int m0 = blockIdx.y * 128, n0 = blockIdx.x * 128;
  int wid = tid >> 6, lane = tid & 63;
  int wr = (wid >> 1) * 64, wc = (wid & 1) * 64;
  int lr = lane & 15, lk = (lane >> 4) * 8;
  f32x4 acc[4][4] = {};

  for (int k0 = 0; k0 < K; k0 += 32) {
#pragma unroll
    for (int i = 0; i < 2; i++) {
      int idx = i * 256 + tid;
      int r = idx >> 2, kc = (idx & 3) * 8;
      glds16(A + (size_t)(m0 + r) * K + k0 + kc, Al + idx * 8);
      glds16(Bt + (size_t)(n0 + r) * K + k0 + kc, Bl + idx * 8);
    }
    __syncthreads();
    bf16x8 af[4], bfr[4];
#pragma unroll
    for (int mi = 0; mi < 4; mi++) af[mi] = *(const bf16x8*)&Al[(wr + mi * 16 + lr) * 32 + lk];
#pragma unroll
    for (int ni = 0; ni < 4; ni++) bfr[ni] = *(const bf16x8*)&Bl[(wc + ni * 16 + lr) * 32 + lk];
#pragma unroll
    for (int mi = 0; mi < 4; mi++)
#pragma unroll
      for (int ni = 0; ni < 4; ni++)
        acc[mi][ni] = __builtin_amdgcn_mfma_f32_16x16x32_bf16(af[mi], bfr[ni], acc[mi][ni], 0, 0, 0);
    __syncthreads();
  }

  int rbase = m0 + wr + ((lane >> 4) << 2);
#pragma unroll
  for (int mi = 0; mi < 4; mi++)
#pragma unroll
    for (int ni = 0; ni < 4; ni++)
#pragma unroll
      for (int r = 0; r < 4; r++) {
        int row = rbase + mi * 16 + r;
        int col = n0 + wc + ni * 16 + lr;
        C[(size_t)row * ldc + col] = (OutT)acc[mi][ni][r];
      }
}

// ---------- RoPE in-place on QKV buffer (q heads + k heads) ----------
__global__ __launch_bounds__(256) void k_rope(bf16* __restrict__ qkv,
                                              const float* __restrict__ fcos,
                                              const float* __restrict__ fsin) {
  int gid = blockIdx.x * 256 + threadIdx.x;  // B*T * 20 heads * 64 pairs
  int row = gid / 1280;
  int p = gid % 1280;
  int head = p >> 6;
  int dp = p & 63;
  int t = row & (SEQT - 1);
  int colbase = head < NH ? head * HD : NH * HD + (head - NH) * HD;
  bf16* ptr = qkv + (size_t)row * 3072 + colbase + dp * 2;
  float a = (float)ptr[0], b = (float)ptr[1];
  float c = fcos[t * 64 + dp], s = fsin[t * 64 + dp];
  ptr[0] = (bf16)(a * c - b * s);
  ptr[1] = (bf16)(a * s + b * c);
}

// ---------- fused causal flash attention, GQA 4:1, 32x32 swapped-QK ----------
// Per block: 128 q rows (4 waves x 32), KV tiles of 64.
// S^T = mfma_32x32x16(Kfrag, Qfrag): lane l holds q=(l&31), kv=crow(r,hi)=
//   (r&3)+8*(r>>2)+4*hi (+16 for the 2nd half, +32 for s1). Softmax
//   in-register; pair combines via __shfl_xor(.,32); P->A-frags via cvt_pk +
//   shfl_xor + select. PV: O[q][d] = mfma(Pfrag, Vfrag from swizzled Vt).
// Rescale (defer-max gated, THR=62 raw = 8/C1) & final 1/l distributed to
//   crow space through a tiny per-wave LDS table.
__global__ __launch_bounds__(256, 2) void k_attn(const bf16* __restrict__ qkv,
                                                 bf16* __restrict__ attout) {
  __shared__ bf16 Kl[2][64 * 128];
  __shared__ bf16 Vt[128][72];
  __shared__ float Atab[4][32];
  int bid = blockIdx.x;
  int qt = 15 - (bid >> 5);  // heavy causal tiles dispatch first
  int bh = bid & 31;
  int b = bh >> 4, h = bh & 15, kvh = h >> 2;
  int tid = threadIdx.x, wid = tid >> 6, lane = tid & 63;
  int li = lane & 31, hi = lane >> 5;
  int q0 = qt * 128;
  int qmin = q0 + wid * 32, qmax = qmin + 31;
  int qlane = qmin + li;
  const float C1 = 0.12751744979927212f;  // (1/sqrt(128)) * log2(e)

  const bf16* kgbase = qkv + (size_t)b * SEQT * 3072 + 2048 + kvh * HD;
  const bf16* vgbase = kgbase + 512;

  // Q B-frags: lane holds Q[qlane][ks*16 + hi*8 .. +8)
  bf16x8 qf[8];
  {
    const bf16* qb = qkv + (size_t)(b * SEQT + qlane) * 3072 + h * HD + hi * 8;
#pragma unroll
    for (int ks = 0; ks < 8; ks++) qf[ks] = *(const bf16x8*)(qb + ks * 16);
  }

  float mrun = -INFINITY, lpart = 0.f;
  f32x16 o0 = {}, o1 = {}, o2 = {}, o3 = {};
  int nkt = 2 * qt + 2;

  // V staging geometry (per thread): 4 kv rows x 8 d columns
  int g = (lane >> 4) & 3;
  int lr = lane & 15;
  int kq4 = (wid * 4 + g) * 4;
  int dc = lr * 8;
  int xr = (lr & 7) << 3;
  int kvw = kq4 ^ xr;

  bf16x8 vr0, vr1, vr2, vr3;

  // ---- prologue: stage tile 0 ----
#pragma unroll
  for (int r = 0; r < 4; r++) {
    int ci = r * 256 + tid;
    int row = ci >> 4;
    int sl = (ci & 15) ^ (row & 15);
    glds16(kgbase + (size_t)row * 3072 + sl * 8, &Kl[0][ci * 8]);
  }
  {
    const bf16* vrow = vgbase + (size_t)kq4 * 3072 + dc;
    vr0 = *(const bf16x8*)(vrow);
    vr1 = *(const bf16x8*)(vrow + 3072);
    vr2 = *(const bf16x8*)(vrow + 6144);
    vr3 = *(const bf16x8*)(vrow + 9216);
  }

  for (int kt = 0; kt < nkt; kt++) {
    int cur = kt & 1;
    int kv0 = kt * 64;
    asm volatile("s_waitcnt vmcnt(0)" ::: "memory");

    // ---- V regs -> Vt (swizzled b64 writes) ----
#pragma unroll
    for (int j = 0; j < 8; j++) {
      bf16x4 w;
      w[0] = vr0[j]; w[1] = vr1[j]; w[2] = vr2[j]; w[3] = vr3[j];
      *(bf16x4*)&Vt[dc + j][kvw] = w;
    }

    // ---- prefetch tile kt+1 (stays in flight across compute) ----
    if (kt + 1 < nkt) {
      int kv1 = kv0 + 64;
      bf16* kdst = &Kl[cur ^ 1][0];
#pragma unroll
      for (int r = 0; r < 4; r++) {
        int ci = r * 256 + tid;
        int row = ci >> 4;
        int sl = (ci & 15) ^ (row & 15);
        glds16(kgbase + (size_t)(kv1 + row) * 3072 + sl * 8, kdst + ci * 8);
      }
      const bf16* vrow = vgbase + (size_t)(kv1 + kq4) * 3072 + dc;
      vr0 = *(const bf16x8*)(vrow);
      vr1 = *(const bf16x8*)(vrow + 3072);
      vr2 = *(const bf16x8*)(vrow + 6144);
      vr3 = *(const bf16x8*)(vrow + 9216);
    }

    asm volatile("s_waitcnt lgkmcnt(0)" ::: "memory");
    __builtin_amdgcn_sched_barrier(0);
    __builtin_amdgcn_s_barrier();
    __builtin_amdgcn_sched_barrier(0);

    if (kv0 <= qmax) {
      // ---- S^T = K Q^T : 2 kv-blocks x 8 k-slices ----
      f32x16 s0 = {}, s1 = {};
      const char* kb0 = (const char*)&Kl[cur][0] + li * 256;
      __builtin_amdgcn_s_setprio(1);
#pragma unroll
      for (int ks = 0; ks < 8; ks++) {
        int off = ((ks * 2 + hi) ^ (li & 15)) << 4;
        bf16x8 kf0 = *(const bf16x8*)(kb0 + off);
        bf16x8 kf1 = *(const bf16x8*)(kb0 + 8192 + off);
        s0 = __builtin_amdgcn_mfma_f32_32x32x16_bf16(kf0, qf[ks], s0, 0, 0, 0);
        s1 = __builtin_amdgcn_mfma_f32_32x32x16_bf16(kf1, qf[ks], s1, 0, 0, 0);
      }
      __builtin_amdgcn_s_setprio(0);

      // ---- causal mask (only when the tile crosses the diagonal) ----
      if (kv0 + 63 > qmin) {
        int base0 = kv0 + 4 * hi - qlane;
#pragma unroll
        for (int r = 0; r < 16; r++) {
          int off = (r & 3) + 8 * (r >> 2);
          if (base0 + off > 0) s0[r] = -INFINITY;
          if (base0 + 32 + off > 0) s1[r] = -INFINITY;
        }
      }

      // ---- row max: 31 in-lane fmax + pair combine via shfl ----
      float pm = s0[0];
#pragma unroll
      for (int r = 1; r < 16; r++) pm = fmaxf(pm, s0[r]);
#pragma unroll
      for (int r = 0; r < 16; r++) pm = fmaxf(pm, s1[r]);
      pm = fmaxf(pm, __shfl_xor(pm, 32));

      // ---- defer-max rescale (rare) ----
      if (!__all(pm - mrun <= 62.0f)) {
        float mnew = fmaxf(mrun, pm);
        float alpha = exp2f((mrun - mnew) * C1);
        mrun = mnew;
        lpart *= alpha;
        Atab[wid][li] = alpha;
        asm volatile("s_waitcnt lgkmcnt(0)" ::: "memory");
        f32x4 a0 = *(const f32x4*)&Atab[wid][4 * hi];
        f32x4 a1 = *(const f32x4*)&Atab[wid][4 * hi + 8];
        f32x4 a2 = *(const f32x4*)&Atab[wid][4 * hi + 16];
        f32x4 a3 = *(const f32x4*)&Atab[wid][4 * hi + 24];
#define RESC_RR(rr, av)                                            \
  _Pragma("unroll") for (int i = 0; i < 4; i++) {                  \
    float f = av[i];                                               \
    o0[rr * 4 + i] *= f; o1[rr * 4 + i] *= f;                      \
    o2[rr * 4 + i] *= f; o3[rr * 4 + i] *= f;                      \
  }
        RESC_RR(0, a0) RESC_RR(1, a1) RESC_RR(2, a2) RESC_RR(3, a3)
#undef RESC_RR
      }

      // ---- exp2 + per-lane partial row-sum (in place) ----
      float mC = mrun * C1;
      float rs = 0.f;
#pragma unroll
      for (int r = 0; r < 16; r++) {
        float p = exp2f(fmaf(s0[r], C1, -mC));
        s0[r] = p; rs += p;
      }
#pragma unroll
      for (int r = 0; r < 16; r++) {
        float p = exp2f(fmaf(s1[r], C1, -mC));
        s1[r] = p; rs += p;
      }
      lpart += rs;

      // ---- pack P -> 4 bf16x8 A-frags (cvt_pk + shfl_xor + select) ----
      union U4 { unsigned int u[4]; bf16x8 v; };
      U4 pa0, pa1, pa2, pa3;
      {
        unsigned int e0 = cvtpk(s0[0], s0[1]), e1 = cvtpk(s0[2], s0[3]);
        unsigned int e2 = cvtpk(s0[4], s0[5]), e3 = cvtpk(s0[6], s0[7]);
        unsigned int e4 = cvtpk(s0[8], s0[9]), e5 = cvtpk(s0[10], s0[11]);
        unsigned int e6 = cvtpk(s0[12], s0[13]), e7 = cvtpk(s0[14], s0[15]);
        unsigned int t0 = __shfl_xor(e0, 32), t1 = __shfl_xor(e1, 32);
        unsigned int t2 = __shfl_xor(e2, 32), t3 = __shfl_xor(e3, 32);
        unsigned int t4 = __shfl_xor(e4, 32), t5 = __shfl_xor(e5, 32);
        unsigned int t6 = __shfl_xor(e6, 32), t7 = __shfl_xor(e7, 32);
        pa0.u[0] = hi ? t2 : e0;  pa0.u[1] = hi ? t3 : e1;
        pa0.u[2] = hi ? e2 : t0;  pa0.u[3] = hi ? e3 : t1;
        pa1.u[0] = hi ? t6 : e4;  pa1.u[1] = hi ? t7 : e5;
        pa1.u[2] = hi ? e6 : t4;  pa1.u[3] = hi ? e7 : t5;
        unsigned int f0 = cvtpk(s1[0], s1[1]), f1 = cvtpk(s1[2], s1[3]);
        unsigned int f2 = cvtpk(s1[4], s1[5]), f3 = cvtpk(s1[6], s1[7]);
        unsigned int f4 = cvtpk(s1[8], s1[9]), f5 = cvtpk(s1[10], s1[11]);
        unsigned int f6 = cvtpk(s1[12], s1[13]), f7 = cvtpk(s1[14], s1[15]);
        unsigned int u0 = __shfl_xor(f0, 32), u1 = __shfl_xor(f1, 32);
        unsigned int u2 = __shfl_xor(f2, 32), u3 = __shfl_xor(f3, 32);
        unsigned int u4 = __shfl_xor(f4, 32), u5 = __shfl_xor(f5, 32);
        unsigned int u6 = __shfl_xor(f6, 32), u7 = __shfl_xor(f7, 32);
        pa2.u[0] = hi ? u2 : f0;  pa2.u[1] = hi ? u3 : f1;
        pa2.u[2] = hi ? f2 : u0;  pa2.u[3] = hi ? f3 : u1;
        pa3.u[0] = hi ? u6 : f4;  pa3.u[1] = hi ? u7 : f5;
        pa3.u[2] = hi ? f6 : u4;  pa3.u[3] = hi ? f7 : u5;
      }

      // ---- O += P V : 4 d-blocks x 4 k-slots ----
      __builtin_amdgcn_s_setprio(1);
#define PV_DB(OACC, DB)                                                      \
  {                                                                          \
    int d = DB * 32 + li;                                                    \
    int xv = ((d >> 3) & 7) << 3;                                            \
    bf16x8 vb0 = *(const bf16x8*)&Vt[d][(hi * 8) ^ xv];                      \
    bf16x8 vb1 = *(const bf16x8*)&Vt[d][(16 + hi * 8) ^ xv];                 \
    bf16x8 vb2 = *(const bf16x8*)&Vt[d][(32 + hi * 8) ^ xv];                 \
    bf16x8 vb3 = *(const bf16x8*)&Vt[d][(48 + hi * 8) ^ xv];                 \
    OACC = __builtin_amdgcn_mfma_f32_32x32x16_bf16(pa0.v, vb0, OACC, 0, 0, 0); \
    OACC = __builtin_amdgcn_mfma_f32_32x32x16_bf16(pa1.v, vb1, OACC, 0, 0, 0); \
    OACC = __builtin_amdgcn_mfma_f32_32x32x16_bf16(pa2.v, vb2, OACC, 0, 0, 0); \
    OACC = __builtin_amdgcn_mfma_f32_32x32x16_bf16(pa3.v, vb3, OACC, 0, 0, 0); \
  }
      PV_DB(o0, 0) PV_DB(o1, 1) PV_DB(o2, 2) PV_DB(o3, 3)
#undef PV_DB
      __builtin_amdgcn_s_setprio(0);
    }

    __builtin_amdgcn_sched_barrier(0);
    __builtin_amdgcn_s_barrier();
    __builtin_amdgcn_sched_barrier(0);
  }

  // ---- epilogue: pair-combine l, distribute 1/l to crow space, store ----
  lpart += __shfl_xor(lpart, 32);
  Atab[wid][li] = 1.f / lpart;
  asm volatile("s_waitcnt lgkmcnt(0)" ::: "memory");
  f32x4 l0 = *(const f32x4*)&Atab[wid][4 * hi];
  f32x4 l1 = *(const f32x4*)&Atab[wid][4 * hi + 8];
  f32x4 l2 = *(const f32x4*)&Atab[wid][4 * hi + 16];
  f32x4 l3 = *(const f32x4*)&Atab[wid][4 * hi + 24];
  {
    size_t obase = (size_t)(b * SEQT) * 2048 + h * HD;
#define STORE_RR(rr, lv)                                                     \
  _Pragma("unroll") for (int i = 0; i < 4; i++) {                            \
    int q = qmin + 4 * hi + 8 * rr + i;                                      \
    size_t rowb = obase + (size_t)q * 2048 + li;                             \
    attout[rowb + 0]  = (bf16)(o0[rr * 4 + i] * lv[i]);                      \
    attout[rowb + 32] = (bf16)(o1[rr * 4 + i] * lv[i]);                      \
    attout[rowb + 64] = (bf16)(o2[rr * 4 + i] * lv[i]);                      \
    attout[rowb + 96] = (bf16)(o3[rr * 4 + i] * lv[i]);                      \
  }
    STORE_RR(0, l0) STORE_RR(1, l1) STORE_RR(2, l2) STORE_RR(3, l3)
#undef STORE_RR
  }
}

extern "C" void kernel_launch(void* const* d_in, const int* in_sizes, int n_in,
                              void* d_out, int out_size, void* d_ws, size_t ws_size,
                              hipStream_t stream) {
  const float* x    = (const float*)d_in[0];
  const float* fcos = (const float*)d_in[1];
  const float* fsin = (const float*)d_in[2];
  const float* wq   = (const float*)d_in[3];
  const float* wk   = (const float*)d_in[4];
  const float* wv   = (const float*)d_in[5];
  const float* wo   = (const float*)d_in[6];
  float* out = (float*)d_out;

  // workspace layout (bytes): [XB/ATT 16.78M][W 12.58M][QKV 25.17M] = ~54.5MB
  char* ws = (char*)d_ws;
  bf16* XB  = (bf16*)ws;                                    // 4096x2048, later attn out
  bf16* W   = (bf16*)(ws + 16777216);                       // 3072x2048 (B^T panel)
  bf16* QKV = (bf16*)(ws + 16777216 + 12582912);            // 4096x3072

  dim3 tb(32, 8);
  k_transpose<<<dim3(64, 64), tb, 0, stream>>>(wq, W, 2048, 2048);
  k_transpose<<<dim3(16, 64), tb, 0, stream>>>(wk, W + 2048 * 2048, 2048, 512);
  k_transpose<<<dim3(16, 64), tb, 0, stream>>>(wv, W + 2560 * 2048, 2048, 512);
  k_convert<<<4096, 256, 0, stream>>>(x, XB, 1048576);
  k_gemm<bf16><<<dim3(24, 32), 256, 0, stream>>>(XB, W, QKV, 4096, 3072, 2048, 3072);
  k_rope<<<20480, 256, 0, stream>>>(QKV, fcos, fsin);
  k_attn<<<512, 256, 0, stream>>>(QKV, XB);
  k_transpose<<<dim3(64, 64), tb, 0, stream>>>(wo, W, 2048, 2048);
  k_gemm<float><<<dim3(16, 32), 256, 0, stream>>>(XB, W, out, 4096, 2048, 2048, 2048);
}